// Round 6
// baseline (53.735 us; speedup 1.0000x reference)
//
#include <hip/hip_runtime.h>

// ---------------------------------------------------------------------------
// UpThreeOffsetsConvShareWeights v7: x direct-from-L2, LDS = weight ring only.
//
// Same algebra (separable deform offsets -> per-phase 2x2x2-tap conv == GEMM
// M=spatial x N=96 x K=512; fused K=96 combine GEMM), C^T convention
// (mfma(W_frag, x_frag), lane = spatial), in-register cvt_pk+permlane32_swap
// relayout, full-line float2 stores (cp looped in-block).
//
// v6 post-mortem: LDS pipe floor (x + w fragments, 2560 b128 x 12cy = 12.8us)
// exceeded the MFMA floor (11us), and the 101KB xt tile forced 1 block/CU.
// v7 splits traffic across pipes:
//  * xT re-laid out as 4 q-regions [32768 sp][16 ch] (32 B/sp) + 128 B zero
//    tail per region. A-fragment = 16 contiguous bytes -> coalesced
//    global_load_dwordx4 from L2 (h0/h1 lanes tile 32-B bricks). Zero pad via
//    OOB redirect of the 32-bit offset to the region tail (branchless).
//    x-reads leave the LDS pipe (now weights-only, 7.7us) for L2 (7.8us).
//  * 4-wave blocks (4x8x8 tile x (a,bph)), grid 512 -> 2 independent
//    blocks/CU; LDS = 48KB ring + 0.25KB bias.
//  * bid remap: phase-siblings of a tile -> same XCD (4x L2 reuse of x).
//  * Ring: 2-tap 24KB chunks, 2 slots, drain-0 vmcnt(0)+barrier (proven).
// ---------------------------------------------------------------------------

typedef __bf16 bf16x8 __attribute__((ext_vector_type(8)));
typedef float f32x16 __attribute__((ext_vector_type(16)));
typedef unsigned u32x2 __attribute__((ext_vector_type(2)));

__device__ inline unsigned short f2bf(float f) {
  unsigned int u = __float_as_uint(f);
  u += 0x7FFFu + ((u >> 16) & 1u);
  return (unsigned short)(u >> 16);
}

__device__ inline bf16x8 bc16(uint4 v) { return __builtin_bit_cast(bf16x8, v); }

__device__ inline unsigned cvtpk(float lo, float hi) {
  unsigned r;
  asm("v_cvt_pk_bf16_f32 %0, %1, %2" : "=v"(r) : "v"(lo), "v"(hi));
  return r;
}

__device__ inline void plswap(unsigned& a, unsigned& b) {
  u32x2 r = __builtin_amdgcn_permlane32_swap(a, b, false, false);
  a = r.x;
  b = r.y;
}

__device__ inline void gload16(const unsigned short* g, unsigned short* l) {
  __builtin_amdgcn_global_load_lds(
      (const __attribute__((address_space(1))) unsigned int*)(const void*)g,
      (__attribute__((address_space(3))) unsigned int*)(void*)l, 16, 0, 0);
}

__device__ inline float ucoef(int abit, int k, int jbit, float alpha) {
  if (abit == 0) return (k == 0) ? (jbit ? alpha : 1.f - alpha) : (jbit ? 1.f : 0.f);
  return (k == 2) ? (jbit ? 1.f - alpha : alpha) : (jbit ? 0.f : 1.f);
}

// xT2 geometry: 4 regions, each 32768 sp * 32 B + 128 B zero tail.
#define XREG_USH 524352   // region stride in ushorts (1,048,704 B)
#define XZERO_B 1048576u  // zero-tail byte offset within a region

// ---------------- K0: all preprocessing in one kernel (2049 blocks) ---------
__global__ void k_prep(const float* __restrict__ x, unsigned short* __restrict__ xT2,
                       const float* __restrict__ w_def, const float* __restrict__ bn1_g,
                       const float* __restrict__ bn1_v, unsigned short* __restrict__ W_sw,
                       const float* __restrict__ w_comb, const float* __restrict__ b_comb,
                       const float* __restrict__ bn2_g, const float* __restrict__ bn2_b,
                       const float* __restrict__ bn2_m, const float* __restrict__ bn2_v,
                       const float* __restrict__ b_def, const float* __restrict__ bn1_b,
                       const float* __restrict__ bn1_m, unsigned short* __restrict__ W2_sw,
                       float* __restrict__ bias1, float* __restrict__ bias2) {
  __shared__ unsigned short t[64][65];
  int bid = blockIdx.x;
  if (bid < 512) {
    int s0 = bid * 64;
    int lane = threadIdx.x & 63;
    int grp = threadIdx.x >> 6;
#pragma unroll
    for (int c = grp; c < 64; c += 4)
      t[c][lane] = f2bf(x[c * 32768 + s0 + lane]);
    __syncthreads();
    int q = lane >> 4, e = lane & 15;  // channel = 16q + e
#pragma unroll
    for (int s = grp; s < 64; s += 4)
      xT2[q * XREG_USH + (size_t)(s0 + s) * 16 + e] = t[lane][s];
  } else if (bid < 2048) {
    int e = (bid - 512) * 256 + threadIdx.x;  // < 393216
    int j = e & 7;
    int lane = (e >> 3) & 63;
    int idx = e >> 9;
    int nt = idx % 3;
    idx /= 3;
    int s = idx & 31;
    int p = idx >> 5;
    int o = lane & 31;
    int br = nt;
    int kk = 16 * s + ((lane >> 5) << 3) + j;
    int tap = kk >> 6, ch = kk & 63;
    int jz = (tap >> 2) & 1, jy = (tap >> 1) & 1, jx = tap & 1;
    int a = (p >> 2) & 1, b = (p >> 1) & 1, cp = p & 1;
    float alpha = (br == 0) ? 0.f : ((br == 1) ? 0.4f : 0.7f);
    const float* wb = w_def + (o * 64 + ch) * 27;
    float sum = 0.f;
    for (int kz = 0; kz < 3; ++kz) {
      float uz = ucoef(a, kz, jz, alpha);
      if (uz == 0.f) continue;
      for (int ky = 0; ky < 3; ++ky) {
        float uy = ucoef(b, ky, jy, alpha);
        if (uy == 0.f) continue;
        float uzy = uz * uy;
        for (int kx = 0; kx < 3; ++kx) {
          float ux = ucoef(cp, kx, jx, alpha);
          if (ux != 0.f) sum += wb[kz * 9 + ky * 3 + kx] * uzy * ux;
        }
      }
    }
    float s1 = bn1_g[o] * rsqrtf(bn1_v[o] + 1e-5f);
    W_sw[e] = f2bf(sum * s1);
  } else {
    int tid = threadIdx.x;
    for (int e = tid; e < 3072; e += 256) {
      int j = e & 7;
      int lane = (e >> 3) & 63;
      int s2 = e >> 9;
      int n = lane & 31;
      int k = 16 * s2 + ((lane >> 5) << 3) + j;
      float sc2 = bn2_g[n] * rsqrtf(bn2_v[n] + 1e-5f);
      W2_sw[e] = f2bf(w_comb[n * 96 + k] * sc2);
    }
    // zero tails of the 4 x-regions (OOB landing pads)
    {
      int q = tid >> 6, e2 = tid & 63;
      xT2[q * XREG_USH + 524288 + e2] = 0;
    }
    if (tid < 32) {
      float s1 = bn1_g[tid] * rsqrtf(bn1_v[tid] + 1e-5f);
      bias1[tid] = (b_def[tid] - bn1_m[tid]) * s1 + bn1_b[tid];
      float s2 = bn2_g[tid] * rsqrtf(bn2_v[tid] + 1e-5f);
      bias2[tid] = (b_comb[tid] - bn2_m[tid]) * s2 + bn2_b[tid];
    }
  }
}

// ---------------- K1: main fused kernel -------------------------------------
// Grid 512 blocks (2/CU), 256 thr (4 waves). bid -> (a,bph) + 4x8x8 tile
// (phase-siblings co-XCD). Wave wv = y-slab. M=64/wave (2 mt x 32 m).
__launch_bounds__(256, 2)
__global__ void k_main(const unsigned short* __restrict__ xT2,
                       const unsigned short* __restrict__ W_sw,
                       const unsigned short* __restrict__ W2_sw,
                       const float* __restrict__ bias1f,
                       const float* __restrict__ bias2f,
                       float* __restrict__ out) {
  __shared__ unsigned short wring[2][12288];  // 2 slots * 24 KB (2 taps each)
  __shared__ float blds[64];                  // bias1 | bias2 tables
  int tid = threadIdx.x;
  int lane = tid & 63;
  int wv = tid >> 6;  // 0..3
  int bid = blockIdx.x;
  int tb = (bid & 7) | ((bid >> 5) << 3);  // tile 0..127
  int ph = (bid >> 3) & 3;
  int bph = ph & 1, a = ph >> 1;
  int tx = tb & 3, ty = (tb >> 2) & 3, tz = tb >> 4;  // tz 0..7
  int i0 = tz * 4, j0 = ty * 8, k0 = tx * 8;

  if (tid < 32) {
    blds[tid] = bias1f[tid];
    blds[32 + tid] = bias2f[tid];
  }

  int h = lane >> 5;
  int m = lane & 31;
  int ax = m & 7, ay = (m >> 3) & 1, az = m >> 4;
  int p0 = (a << 2) | (bph << 1);
  unsigned hb = (unsigned)(h << 4);  // h*16 bytes

  const char* xq0 = (const char*)xT2;
  const char* xq1 = xq0 + 1048704;
  const char* xq2 = xq0 + 2097408;
  const char* xq3 = xq0 + 3146112;

  // chunk cc (0..7): phase p0|(cc>>2), taps {2(cc&3), 2(cc&3)+1} = 24576 B.
  // 4 waves x 6144 B each = 6 x width-16 wave-instructions.
  auto stage = [&](int cc) {
    int pn = p0 | (cc >> 2);
    const unsigned short* g =
        W_sw + pn * 49152 + (cc & 3) * 12288 + wv * 3072 + lane * 8;
    unsigned short* l = &wring[cc & 1][wv * 3072];
#pragma unroll
    for (int k = 0; k < 6; ++k) gload16(g + k * 512, l + k * 512);
  };

  __syncthreads();  // blds visible before the loop's barriers
  stage(0);         // prologue: chunk 0 in flight

  f32x16 osv0, osv1;  // cp=0 results, held across cp=1
  f32x16 acc[2][3];
#pragma unroll
  for (int mt = 0; mt < 2; ++mt)
#pragma unroll
    for (int nt = 0; nt < 3; ++nt) acc[mt][nt] = (f32x16)0.f;

  for (int cc = 0; cc < 8; ++cc) {
    asm volatile("s_waitcnt vmcnt(0)" ::: "memory");  // own chunk-cc loads in
    __builtin_amdgcn_s_barrier();                     // all waves' parts in
    __builtin_amdgcn_sched_barrier(0);
    if (cc < 7) stage(cc + 1);  // next chunk flies during this chunk's work
    __builtin_amdgcn_sched_barrier(0);

    // per-chunk x offsets: chunk -> (cp, jy, jz); tl = jx; mt -> z+2
    int cp = cc >> 2, jy = cc & 1, jz = (cc >> 1) & 1;
    int gz0i = i0 + a - 1 + az + jz;
    int gz1i = gz0i + 2;
    int gyi = j0 + bph - 1 + 2 * wv + ay + jy;
    int gx0i = k0 - 1 + ax + cp;
    int gx1i = gx0i + 1;
    bool oky = (unsigned)gyi < 32u;
    bool okz0 = (unsigned)gz0i < 32u, okz1 = (unsigned)gz1i < 32u;
    bool okx0 = (unsigned)gx0i < 32u, okx1 = (unsigned)gx1i < 32u;
    unsigned s00 = (unsigned)(((gz0i * 32 + gyi) * 32 + gx0i) * 32) + hb;
    unsigned s01 = (unsigned)(((gz1i * 32 + gyi) * 32 + gx0i) * 32) + hb;
    unsigned s10 = (unsigned)(((gz0i * 32 + gyi) * 32 + gx1i) * 32) + hb;
    unsigned s11 = (unsigned)(((gz1i * 32 + gyi) * 32 + gx1i) * 32) + hb;
    unsigned v00 = (oky && okz0 && okx0) ? s00 : XZERO_B;
    unsigned v01 = (oky && okz1 && okx0) ? s01 : XZERO_B;
    unsigned v10 = (oky && okz0 && okx1) ? s10 : XZERO_B;
    unsigned v11 = (oky && okz1 && okx1) ? s11 : XZERO_B;

    const unsigned short* wfb = &wring[cc & 1][lane * 8];
#pragma unroll
    for (int tl = 0; tl < 2; ++tl) {
      unsigned va0 = tl ? v10 : v00;
      unsigned va1 = tl ? v11 : v01;
#pragma unroll
      for (int q = 0; q < 4; ++q) {
        const char* xb = (q == 0) ? xq0 : (q == 1) ? xq1 : (q == 2) ? xq2 : xq3;
        bf16x8 a0 = bc16(*(const uint4*)(xb + va0));
        bf16x8 a1 = bc16(*(const uint4*)(xb + va1));
        const unsigned short* wf = wfb + tl * 6144 + q * 1536;
        bf16x8 bb0 = bc16(*(const uint4*)(wf));
        bf16x8 bb1 = bc16(*(const uint4*)(wf + 512));
        bf16x8 bb2 = bc16(*(const uint4*)(wf + 1024));
        __builtin_amdgcn_s_setprio(1);
        acc[0][0] = __builtin_amdgcn_mfma_f32_32x32x16_bf16(bb0, a0, acc[0][0], 0, 0, 0);
        acc[1][0] = __builtin_amdgcn_mfma_f32_32x32x16_bf16(bb0, a1, acc[1][0], 0, 0, 0);
        acc[0][1] = __builtin_amdgcn_mfma_f32_32x32x16_bf16(bb1, a0, acc[0][1], 0, 0, 0);
        acc[1][1] = __builtin_amdgcn_mfma_f32_32x32x16_bf16(bb1, a1, acc[1][1], 0, 0, 0);
        acc[0][2] = __builtin_amdgcn_mfma_f32_32x32x16_bf16(bb2, a0, acc[0][2], 0, 0, 0);
        acc[1][2] = __builtin_amdgcn_mfma_f32_32x32x16_bf16(bb2, a1, acc[1][2], 0, 0, 0);
        __builtin_amdgcn_s_setprio(0);
      }
    }

    if (cc == 3) {
      // ---- cp=0 epilogue: BN1+ReLU, in-reg relayout, combine, BN2+ReLU ----
      const uint4* w2q = (const uint4*)W2_sw;
#pragma unroll
      for (int mt = 0; mt < 2; ++mt) {
        uint4 fr[6];
#pragma unroll
        for (int nt = 0; nt < 3; ++nt) {
          unsigned ww[8];
#pragma unroll
          for (int qc = 0; qc < 8; ++qc) {
            int q = qc >> 1, c2 = qc & 1;
            int r0 = 4 * q + 2 * c2;
            int row = (r0 & 3) + ((r0 >> 2) << 3) + (h << 2);
            float lo = fmaxf(acc[mt][nt][r0] + blds[row], 0.f);
            float hi = fmaxf(acc[mt][nt][r0 + 1] + blds[row + 1], 0.f);
            ww[2 * q + c2] = cvtpk(lo, hi);
          }
          plswap(ww[0], ww[2]);
          plswap(ww[1], ww[3]);
          plswap(ww[4], ww[6]);
          plswap(ww[5], ww[7]);
          fr[2 * nt] = make_uint4(ww[0], ww[1], ww[2], ww[3]);
          fr[2 * nt + 1] = make_uint4(ww[4], ww[5], ww[6], ww[7]);
        }
        f32x16 acc2 = (f32x16)0.f;
#pragma unroll
        for (int s2 = 0; s2 < 6; ++s2)
          acc2 = __builtin_amdgcn_mfma_f32_32x32x16_bf16(bc16(w2q[s2 * 64 + lane]),
                                                         bc16(fr[s2]), acc2, 0, 0, 0);
        f32x16 ov;
#pragma unroll
        for (int r = 0; r < 16; ++r) {
          int row = (r & 3) + ((r >> 2) << 3) + (h << 2);
          ov[r] = fmaxf(acc2[r] + blds[32 + row], 0.f);
        }
        if (mt == 0) osv0 = ov; else osv1 = ov;
#pragma unroll
        for (int nt = 0; nt < 3; ++nt) acc[mt][nt] = (f32x16)0.f;
      }
    }
  }

  // ---- cp=1 epilogue: same pipeline + full-line float2 stores ----
  {
    const uint4* w2q = (const uint4*)W2_sw;
#pragma unroll
    for (int mt = 0; mt < 2; ++mt) {
      uint4 fr[6];
#pragma unroll
      for (int nt = 0; nt < 3; ++nt) {
        unsigned ww[8];
#pragma unroll
        for (int qc = 0; qc < 8; ++qc) {
          int q = qc >> 1, c2 = qc & 1;
          int r0 = 4 * q + 2 * c2;
          int row = (r0 & 3) + ((r0 >> 2) << 3) + (h << 2);
          float lo = fmaxf(acc[mt][nt][r0] + blds[row], 0.f);
          float hi = fmaxf(acc[mt][nt][r0 + 1] + blds[row + 1], 0.f);
          ww[2 * q + c2] = cvtpk(lo, hi);
        }
        plswap(ww[0], ww[2]);
        plswap(ww[1], ww[3]);
        plswap(ww[4], ww[6]);
        plswap(ww[5], ww[7]);
        fr[2 * nt] = make_uint4(ww[0], ww[1], ww[2], ww[3]);
        fr[2 * nt + 1] = make_uint4(ww[4], ww[5], ww[6], ww[7]);
      }
      f32x16 acc2 = (f32x16)0.f;
#pragma unroll
      for (int s2 = 0; s2 < 6; ++s2)
        acc2 = __builtin_amdgcn_mfma_f32_32x32x16_bf16(bc16(w2q[s2 * 64 + lane]),
                                                       bc16(fr[s2]), acc2, 0, 0, 0);
      f32x16 prev = (mt == 0) ? osv0 : osv1;
      int Z = 2 * (i0 + 2 * mt + az) + a;
      int Y = 2 * (j0 + 2 * wv + ay) + bph;
      float2* o2 = (float2*)out;
#pragma unroll
      for (int r = 0; r < 16; ++r) {
        int ch = (r & 3) + ((r >> 2) << 3) + (h << 2);
        float v1 = fmaxf(acc2[r] + blds[32 + ch], 0.f);
        o2[((size_t)ch << 17) + ((size_t)Z << 11) + (Y << 5) + (k0 + ax)] =
            make_float2(prev[r], v1);
      }
    }
  }
}

// ---------------------------------------------------------------------------
extern "C" void kernel_launch(void* const* d_in, const int* in_sizes, int n_in,
                              void* d_out, int out_size, void* d_ws, size_t ws_size,
                              hipStream_t stream) {
  (void)in_sizes; (void)n_in; (void)out_size; (void)ws_size;
  const float* x      = (const float*)d_in[0];
  const float* w_def  = (const float*)d_in[1];
  const float* b_def  = (const float*)d_in[2];
  const float* bn1_g  = (const float*)d_in[3];
  const float* bn1_b  = (const float*)d_in[4];
  const float* bn1_m  = (const float*)d_in[5];
  const float* bn1_v  = (const float*)d_in[6];
  const float* w_comb = (const float*)d_in[7];
  const float* b_comb = (const float*)d_in[8];
  const float* bn2_g  = (const float*)d_in[9];
  const float* bn2_b  = (const float*)d_in[10];
  const float* bn2_m  = (const float*)d_in[11];
  const float* bn2_v  = (const float*)d_in[12];

  char* ws = (char*)d_ws;
  unsigned short* xT2  = (unsigned short*)(ws);             // 4,194,816 B
  unsigned short* W_sw = (unsigned short*)(ws + 4194816);   //   786,432 B
  unsigned short* W2sw = (unsigned short*)(ws + 4981248);   //     6,144 B
  float* bias1 = (float*)(ws + 4987392);                    //       128 B
  float* bias2 = (float*)(ws + 4987520);                    //       128 B
  float* out = (float*)d_out;

  hipLaunchKernelGGL(k_prep, dim3(2049), dim3(256), 0, stream,
                     x, xT2, w_def, bn1_g, bn1_v, W_sw,
                     w_comb, b_comb, bn2_g, bn2_b, bn2_m, bn2_v,
                     b_def, bn1_b, bn1_m, W2sw, bias1, bias2);
  hipLaunchKernelGGL(k_main, dim3(512), dim3(256), 0, stream,
                     xT2, W_sw, W2sw, bias1, bias2, out);
}